// Round 8
// baseline (292.680 us; speedup 1.0000x reference)
//
#include <hip/hip_runtime.h>

#define N 8192
#define D 64

typedef unsigned short ushort_t;
typedef unsigned long long u64;
typedef __attribute__((ext_vector_type(8))) short bf16x8;
typedef __attribute__((ext_vector_type(4))) float f32x4;

// exp(cos/T) = exp(2*cos) = exp2(cos * 2/ln2). sqrt(2/ln2) is folded into BOTH
// normalized operands, so the MFMA dot product directly yields exp2's argument.
#define SQRT_2_OVER_LN2 1.6986436f

// Single v_exp_f32 via the compiler-known builtin (handles TRANS hazards).
#if __has_builtin(__builtin_amdgcn_exp2f)
#define EXP2F(x) __builtin_amdgcn_exp2f(x)
#else
#define EXP2F(x) exp2f(x)
#endif

__device__ inline ushort_t f32_to_bf16(float f) {
    union { float f; unsigned u; } c; c.f = f;
    unsigned r = (c.u + 0x7FFFu + ((c.u >> 16) & 1u)) >> 16;
    return (ushort_t)r;
}

// ---------------- kernel 1: L2-normalize rows, scale, emit bf16 ---------
// Also zeroes the 64K-float accum buffer (blocks 0..255).
__global__ void normalize_kernel(const float* __restrict__ z_mp,
                                 const float* __restrict__ z_sc,
                                 ushort_t* __restrict__ zn,
                                 float* __restrict__ accum) {
    if (blockIdx.x < 256) accum[blockIdx.x * 256 + threadIdx.x] = 0.0f;
    int lane = threadIdx.x & 63;
    int row  = blockIdx.x * 4 + (threadIdx.x >> 6);
    const float* src = (row < N) ? z_mp : z_sc;
    int srow = row & (N - 1);
    float x = src[srow * D + lane];
    float s = x * x;
    #pragma unroll
    for (int m = 32; m; m >>= 1) s += __shfl_xor(s, m, 64);
    float n = sqrtf(s);
    float scale = SQRT_2_OVER_LN2 / fmaxf(n, 1e-12f);
    zn[row * D + lane] = f32_to_bf16(x * scale);
}

// ---------------- kernel 1b: compress pos (f32 0/1) -> bitmask ----------
// mask[row*128 + jw] bit j = (pos[row][jw*64+j] != 0). 8 MB total.
__global__ __launch_bounds__(256) void compress_kernel(
        const float* __restrict__ pos,
        u64* __restrict__ mask) {
    int lane = threadIdx.x & 63;
    size_t wv = (size_t)blockIdx.x * 4 + (threadIdx.x >> 6);
    size_t nw = (size_t)gridDim.x * 4;
    const size_t units = (size_t)N * N / 256;   // 256 cols per wave-iter
    for (size_t u = wv; u < units; u += nw) {
        const float* base = pos + u * 256 + lane;
        u64 w0 = __ballot(base[0]   > 0.5f);
        u64 w1 = __ballot(base[64]  > 0.5f);
        u64 w2 = __ballot(base[128] > 0.5f);
        u64 w3 = __ballot(base[192] > 0.5f);
        if (lane == 0) {
            u64* mb = mask + u * 4;
            mb[0] = w0; mb[1] = w1; mb[2] = w2; mb[3] = w3;
        }
    }
}

// ---------------- kernel 2: symmetric tiled similarity ------------------
// Each exp-tile M[i][j] = exp2(zA[i].zB[j]) is computed ONCE and accumulated
// BOTH ways:
//   row-side (term A2B): rs[i] += sum_j M, ps[i] += sum_j M*pos[i][j]
//   col-side (term B2A): rs[j] += sum_i M, ps[j] += sum_i M*pos[j][i]
// (since m_B2A[j][i] = M[i][j]). Symmetric pairs (mp,mp)/(sc,sc) enumerate
// only the lower triangle tj <= ti (col-side skipped on tj==ti); pair
// (mp,sc) enumerates the full grid. Total tile work = 2.0x less than R6.
// Grid: (cjq=8, ti=128, pair=3); wave w owns chunk cj=cjq*4+w of 4 tiles.
__global__ __launch_bounds__(256, 3) void contrast_main(
        const ushort_t* __restrict__ zn,
        const unsigned* __restrict__ mask32,
        const u64* __restrict__ mask64,
        float* __restrict__ accum) {
    int lane = threadIdx.x & 63;
    int w    = threadIdx.x >> 6;
    int cj   = blockIdx.x * 4 + w;     // col-chunk 0..31
    int ti   = blockIdx.y;             // row tile 0..127
    int p    = blockIdx.z;             // pair 0:(mp,sc) 1:(mp,mp) 2:(sc,sc)

    if (p > 0 && 4 * cj > ti) return;  // whole-wave early exit (no barriers)

    int a     = (p == 2) ? 1 : 0;          // A source
    int bsel  = (p == 0) ? 1 : a;          // B source
    int termR = (p == 0) ? 0 : (p == 1 ? 2 : 3);
    int termC = (p == 0) ? 1 : termR;

    int rq = lane >> 4;                // 0..3
    int lc = lane & 15;                // 0..15
    unsigned sh = (unsigned)(lc & 7) * 4;   // row-mask nibble shift (u32 word)

    const ushort_t* Az = zn + a * (N * D);
    const ushort_t* Bz = zn + bsel * (N * D);
    int I0 = ti * 64;

    // A fragments: row = I0 + 16r + lc, k = s*32 + rq*8 (held across tiles)
    bf16x8 af[4][2];
    #pragma unroll
    for (int r = 0; r < 4; ++r)
        #pragma unroll
        for (int s = 0; s < 2; ++s)
            af[r][s] = *(const bf16x8*)(Az + (I0 + 16 * r + lc) * D + s * 32 + rq * 8);

    float rs_acc[4][4], ps_acc[4][4];
    #pragma unroll
    for (int r = 0; r < 4; ++r)
        #pragma unroll
        for (int e = 0; e < 4; ++e) { rs_acc[r][e] = 0.0f; ps_acc[r][e] = 0.0f; }

    #pragma unroll 1
    for (int tjs = 0; tjs < 4; ++tjs) {
        int tj = cj * 4 + tjs;
        if (p > 0 && tj > ti) break;       // triangle bound
        int J = tj * 64;
        bool colside = (p == 0) || (tj != ti);

        // B fragments, permuted: fragment c <- row (J + 4*lc + c)
        bf16x8 bf[4][2];
        #pragma unroll
        for (int c = 0; c < 4; ++c)
            #pragma unroll
            for (int s = 0; s < 2; ++s)
                bf[c][s] = *(const bf16x8*)(Bz + (J + 4 * lc + c) * D + s * 32 + rq * 8);

        // col-side mask: rows j = J+4lc+c of mask, u64 word I0>>6, bit = i-I0
        u64 cw[4];
        #pragma unroll
        for (int c = 0; c < 4; ++c)
            cw[c] = mask64[(size_t)(J + 4 * lc + c) * (N / 64) + (I0 >> 6)];

        // row-side mask base: rows i = I0+rq*4+16r+e, u32 word (J>>5)+(lc>>3)
        const unsigned* mr = mask32 + (size_t)(I0 + rq * 4) * (N / 32)
                                     + (J >> 5) + (lc >> 3);

        // per-tile column accumulators (cols 4lc+c)
        float cs[4] = {0.f, 0.f, 0.f, 0.f};
        float pst[4] = {0.f, 0.f, 0.f, 0.f};

        #pragma unroll
        for (int r = 0; r < 4; ++r) {
            unsigned mwv[4];
            #pragma unroll
            for (int e = 0; e < 4; ++e)
                mwv[e] = mr[(size_t)(16 * r + e) * (N / 32)];

            f32x4 acc[4];
            #pragma unroll
            for (int c = 0; c < 4; ++c) acc[c] = (f32x4){0.f, 0.f, 0.f, 0.f};
            #pragma unroll
            for (int s = 0; s < 2; ++s)
                #pragma unroll
                for (int c = 0; c < 4; ++c)
                    acc[c] = __builtin_amdgcn_mfma_f32_16x16x32_bf16(
                        af[r][s], bf[c][s], acc[c], 0, 0, 0);

            unsigned shc = (unsigned)(16 * r + rq * 4);   // col-mask shift
            #pragma unroll
            for (int c = 0; c < 4; ++c) {
                unsigned nibC = (unsigned)(cw[c] >> shc) & 0xFu;
                #pragma unroll
                for (int e = 0; e < 4; ++e) {
                    float q = EXP2F(acc[c][e]);
                    rs_acc[r][e] += q;
                    ps_acc[r][e] = fmaf(q, (float)((mwv[e] >> (sh + c)) & 1u),
                                        ps_acc[r][e]);
                    cs[c] += q;
                    pst[c] = fmaf(q, (float)((nibC >> e) & 1u), pst[c]);
                }
            }
        }

        // col-side reduce over the 4 rq-groups (lane bits 4,5) + atomics
        if (colside) {
            #pragma unroll
            for (int c = 0; c < 4; ++c) {
                float v1 = cs[c], v2 = pst[c];
                v1 += __shfl_xor(v1, 16, 64); v1 += __shfl_xor(v1, 32, 64);
                v2 += __shfl_xor(v2, 16, 64); v2 += __shfl_xor(v2, 32, 64);
                if (rq == 0) {
                    int gj = J + 4 * lc + c;
                    atomicAdd(&accum[termC * 2 * N + gj],     v1);
                    atomicAdd(&accum[termC * 2 * N + N + gj], v2);
                }
            }
        }
    }

    // row-side butterfly over the 16 lanes sharing each row (lane bits 0..3)
    #pragma unroll
    for (int r = 0; r < 4; ++r)
        #pragma unroll
        for (int e = 0; e < 4; ++e) {
            float rs = rs_acc[r][e], ps = ps_acc[r][e];
            #pragma unroll
            for (int m = 1; m < 16; m <<= 1) {
                rs += __shfl_xor(rs, m, 64);
                ps += __shfl_xor(ps, m, 64);
            }
            if (lc == 0) {
                int gi = I0 + 16 * r + rq * 4 + e;
                atomicAdd(&accum[termR * 2 * N + gi],     rs);
                atomicAdd(&accum[termR * 2 * N + N + gi], ps);
            }
        }
}

// ---------------- kernel 3: final loss reduction ------------------------
__global__ void finalize_kernel(const float* __restrict__ accum,
                                float* __restrict__ out) {
    __shared__ float red[256];
    float local = 0.0f;
    for (int i = threadIdx.x; i < N; i += 256) {
        float s = 0.0f;
        #pragma unroll
        for (int t = 0; t < 4; ++t) {
            float rs = accum[t * 2 * N + i];
            float ps = accum[t * 2 * N + N + i];
            s += logf(ps / (rs + 1e-8f));
        }
        local += s;
    }
    red[threadIdx.x] = local;
    __syncthreads();
    for (int m = 128; m; m >>= 1) {
        if (threadIdx.x < m) red[threadIdx.x] += red[threadIdx.x + m];
        __syncthreads();
    }
    if (threadIdx.x == 0) out[0] = -red[0] / (float)N;
}

extern "C" void kernel_launch(void* const* d_in, const int* in_sizes, int n_in,
                              void* d_out, int out_size, void* d_ws, size_t ws_size,
                              hipStream_t stream) {
    const float* z_mp = (const float*)d_in[0];
    const float* z_sc = (const float*)d_in[1];
    const float* pos  = (const float*)d_in[2];
    float* out = (float*)d_out;

    ushort_t* zn = (ushort_t*)d_ws;                                       // 2 MB
    float* accum = (float*)((char*)d_ws + (size_t)2 * N * D * sizeof(ushort_t));   // 256 KB
    u64* mask = (u64*)((char*)accum + (size_t)4 * 2 * N * sizeof(float)); // 8 MB

    normalize_kernel<<<(2 * N) / 4, 256, 0, stream>>>(z_mp, z_sc, zn, accum);
    compress_kernel<<<2048, 256, 0, stream>>>(pos, mask);
    dim3 grid(8, 128, 3);
    contrast_main<<<grid, 256, 0, stream>>>(zn, (const unsigned*)mask, mask, accum);
    finalize_kernel<<<1, 256, 0, stream>>>(accum, out);
}

// Round 9
// 183.114 us; speedup vs baseline: 1.5983x; 1.5983x over previous
//
#include <hip/hip_runtime.h>

#define N 8192
#define D 64
#define JSPLIT 16
#define JSTEPS (N / 64 / JSPLIT)   // 8 J-tiles of 64 cols per block

typedef unsigned short ushort_t;
typedef unsigned long long u64;
typedef __attribute__((ext_vector_type(8))) short bf16x8;
typedef __attribute__((ext_vector_type(4))) float f32x4;

// exp(cos/T) = exp(2*cos) = exp2(cos * 2/ln2). sqrt(2/ln2) is folded into BOTH
// normalized operands, so the MFMA dot product directly yields exp2's argument.
#define SQRT_2_OVER_LN2 1.6986436f

#if __has_builtin(__builtin_amdgcn_exp2f)
#define EXP2F(x) __builtin_amdgcn_exp2f(x)
#else
#define EXP2F(x) exp2f(x)
#endif

typedef __attribute__((address_space(1))) const unsigned int g_u32;
typedef __attribute__((address_space(3))) unsigned int       l_u32;

__device__ inline ushort_t f32_to_bf16(float f) {
    union { float f; unsigned u; } c; c.f = f;
    unsigned r = (c.u + 0x7FFFu + ((c.u >> 16) & 1u)) >> 16;
    return (ushort_t)r;
}

// ---------------- kernel 1: L2-normalize rows, scale, emit bf16 ---------
// Also zeroes the 64K-float accum buffer (blocks 0..255).
__global__ void normalize_kernel(const float* __restrict__ z_mp,
                                 const float* __restrict__ z_sc,
                                 ushort_t* __restrict__ zn,
                                 float* __restrict__ accum) {
    if (blockIdx.x < 256) accum[blockIdx.x * 256 + threadIdx.x] = 0.0f;
    int lane = threadIdx.x & 63;
    int row  = blockIdx.x * 4 + (threadIdx.x >> 6);
    const float* src = (row < N) ? z_mp : z_sc;
    int srow = row & (N - 1);
    float x = src[srow * D + lane];
    float s = x * x;
    #pragma unroll
    for (int m = 32; m; m >>= 1) s += __shfl_xor(s, m, 64);
    float n = sqrtf(s);
    float scale = SQRT_2_OVER_LN2 / fmaxf(n, 1e-12f);
    zn[row * D + lane] = f32_to_bf16(x * scale);
}

// ---------------- kernel 1b: compress pos (f32 0/1) -> bitmask ----------
// mask[row*128 + jw] bit j = (pos[row][jw*64+j] != 0). 8 MB total.
__global__ __launch_bounds__(256) void compress_kernel(
        const float* __restrict__ pos,
        u64* __restrict__ mask) {
    int lane = threadIdx.x & 63;
    size_t wv = (size_t)blockIdx.x * 4 + (threadIdx.x >> 6);
    size_t nw = (size_t)gridDim.x * 4;
    const size_t units = (size_t)N * N / 256;   // 256 cols per wave-iter
    for (size_t u = wv; u < units; u += nw) {
        const float* base = pos + u * 256 + lane;
        u64 w0 = __ballot(base[0]   > 0.5f);
        u64 w1 = __ballot(base[64]  > 0.5f);
        u64 w2 = __ballot(base[128] > 0.5f);
        u64 w3 = __ballot(base[192] > 0.5f);
        if (lane == 0) {
            u64* mb = mask + u * 4;
            mb[0] = w0; mb[1] = w1; mb[2] = w2; mb[3] = w3;
        }
    }
}

// ---------------- kernel 2: tiled 4-pair similarity + row accumulation --
// 4 waves/block on the same 64x64 (I,J) tile; wave w -> term (a=w>>1, b=w&1).
// B-panels (one per b-source) staged to LDS per jj, double-buffered,
// coalesced global_load_lds with PRE-SWIZZLED source (involution
// swz(row) = ((row>>2)&7)<<4 on the byte offset within the 128B row), so
// swizzled ds_read_b128 fragment reads are bank-conflict-free.
// Column permutation: B-fragment c <- panel row (4*lc + c), so a lane's 4
// output columns are the contiguous quad 4lc..4lc+3 -> pos bits are one
// nibble of a u32 mask word.
__global__ __launch_bounds__(256, 3) void contrast_main(
        const ushort_t* __restrict__ zn,
        const unsigned* __restrict__ mask32,
        float* __restrict__ accum) {
    __shared__ char lds[2][2][8192];   // [buf][panel(b-source)][64 rows x 128B]

    int lane = threadIdx.x & 63;
    int w    = threadIdx.x >> 6;       // wave 0..3
    int a = w >> 1, b = w & 1;         // 0=mp, 1=sc
    int term = (a == 0) ? (b == 0 ? 2 : 0) : (b == 0 ? 1 : 3);
    int rq = lane >> 4;                // 0..3
    int lc = lane & 15;                // 0..15
    unsigned sh = (unsigned)(lc & 7) * 4;   // nibble shift within u32

    const ushort_t* Az = zn + a * (N * D);
    int I0 = blockIdx.x * 64;
    int J0 = blockIdx.y * (N / JSPLIT);

    // A fragments: row = I0 + 16r + lc, k = s*32 + rq*8 .. +8 (held all loop)
    bf16x8 af[4][2];
    #pragma unroll
    for (int r = 0; r < 4; ++r)
        #pragma unroll
        for (int s = 0; s < 2; ++s)
            af[r][s] = *(const bf16x8*)(Az + (I0 + 16 * r + lc) * D + s * 32 + rq * 8);

    // staging role: waves 0,1 -> panel 0 (mp); waves 2,3 -> panel 1 (sc).
    // wave covers rows 32*(w&1)..+32 of its panel (4 instrs x 8 rows).
    {
        // precompute per-lane swizzled source offset pieces (row-local)
    }
    int pan  = w >> 1;
    int half = w & 1;
    const char* gpan = (const char*)(zn + (size_t)pan * N * D) + (size_t)J0 * 2 * D;

    #define STAGE(bufv, jjv) do {                                              \
        const char* gb_ = gpan + (size_t)(jjv) * 64 * 128;                     \
        char* lb_ = &lds[bufv][pan][half * 4096];                              \
        _Pragma("unroll")                                                      \
        for (int i_ = 0; i_ < 4; ++i_) {                                       \
            int row_ = half * 32 + i_ * 8 + (lane >> 3);                       \
            int bsw_ = ((lane & 7) * 16) ^ (((row_ >> 2) & 7) << 4);           \
            __builtin_amdgcn_global_load_lds(                                  \
                (g_u32*)(gb_ + row_ * 128 + bsw_),                             \
                (l_u32*)(lb_ + i_ * 1024), 16, 0, 0);                          \
        }                                                                      \
    } while (0)

    // u32 view of mask: row stride N/32=256 words; 64 cols = 2 words per jj.
    const unsigned* mrow = mask32 + (size_t)(I0 + rq * 4) * (N / 32)
                                  + (J0 >> 5) + (lc >> 3);

    float rs_acc[4][4], ps_acc[4][4];
    #pragma unroll
    for (int r = 0; r < 4; ++r)
        #pragma unroll
        for (int e = 0; e < 4; ++e) { rs_acc[r][e] = 0.0f; ps_acc[r][e] = 0.0f; }

    // fragment ds_read byte offsets within the b-panel (swizzled):
    // frag (c,s): row = 4*lc+c, logical byte = s*64 + rq*16, swz = (lc&7)<<4
    const char* mypan_base[2] = { &lds[0][b][0], &lds[1][b][0] };
    unsigned fswz = ((unsigned)(lc & 7)) << 4;

    STAGE(0, 0);
    __syncthreads();

    #pragma unroll 1
    for (int jj = 0; jj < JSTEPS; ++jj) {
        int buf = jj & 1;
        if (jj + 1 < JSTEPS) STAGE(buf ^ 1, jj + 1);   // lands by next barrier

        // B fragments from LDS (swizzled, conflict-free)
        const char* pb = mypan_base[buf];
        bf16x8 bf[4][2];
        #pragma unroll
        for (int c = 0; c < 4; ++c)
            #pragma unroll
            for (int s = 0; s < 2; ++s)
                bf[c][s] = *(const bf16x8*)(pb + (4 * lc + c) * 128
                                              + (((unsigned)(s * 64 + rq * 16)) ^ fswz));

        #pragma unroll
        for (int r = 0; r < 4; ++r) {
            unsigned mwv[4];
            #pragma unroll
            for (int e = 0; e < 4; ++e)
                mwv[e] = mrow[(size_t)(16 * r + e) * (N / 32) + jj * 2];

            f32x4 acc[4];
            #pragma unroll
            for (int c = 0; c < 4; ++c) acc[c] = (f32x4){0.f, 0.f, 0.f, 0.f};
            #pragma unroll
            for (int s = 0; s < 2; ++s)
                #pragma unroll
                for (int c = 0; c < 4; ++c)
                    acc[c] = __builtin_amdgcn_mfma_f32_16x16x32_bf16(
                        af[r][s], bf[c][s], acc[c], 0, 0, 0);

            #pragma unroll
            for (int e = 0; e < 4; ++e) {
                unsigned nib = (mwv[e] >> sh) & 0xFu;
                float rs = rs_acc[r][e], ps = ps_acc[r][e];
                #pragma unroll
                for (int c = 0; c < 4; ++c) {
                    float eV = EXP2F(acc[c][e]);           // arg pre-scaled
                    rs += eV;
                    ps = fmaf((float)((nib >> c) & 1u), eV, ps);
                }
                rs_acc[r][e] = rs; ps_acc[r][e] = ps;
            }
        }
        __syncthreads();   // staging done + everyone finished reading buf
    }
    #undef STAGE

    // butterfly-reduce across the 16 lanes sharing each row (lane bits 0..3)
    #pragma unroll
    for (int r = 0; r < 4; ++r)
        #pragma unroll
        for (int e = 0; e < 4; ++e) {
            float rs = rs_acc[r][e], ps = ps_acc[r][e];
            #pragma unroll
            for (int m = 1; m < 16; m <<= 1) {
                rs += __shfl_xor(rs, m, 64);
                ps += __shfl_xor(ps, m, 64);
            }
            if (lc == 0) {
                int gi = I0 + 16 * r + rq * 4 + e;
                atomicAdd(&accum[term * 2 * N + gi],     rs);
                atomicAdd(&accum[term * 2 * N + N + gi], ps);
            }
        }
}

// ---------------- kernel 3: final loss reduction ------------------------
__global__ void finalize_kernel(const float* __restrict__ accum,
                                float* __restrict__ out) {
    __shared__ float red[256];
    float local = 0.0f;
    for (int i = threadIdx.x; i < N; i += 256) {
        float s = 0.0f;
        #pragma unroll
        for (int t = 0; t < 4; ++t) {
            float rs = accum[t * 2 * N + i];
            float ps = accum[t * 2 * N + N + i];
            s += logf(ps / (rs + 1e-8f));
        }
        local += s;
    }
    red[threadIdx.x] = local;
    __syncthreads();
    for (int m = 128; m; m >>= 1) {
        if (threadIdx.x < m) red[threadIdx.x] += red[threadIdx.x + m];
        __syncthreads();
    }
    if (threadIdx.x == 0) out[0] = -red[0] / (float)N;
}

extern "C" void kernel_launch(void* const* d_in, const int* in_sizes, int n_in,
                              void* d_out, int out_size, void* d_ws, size_t ws_size,
                              hipStream_t stream) {
    const float* z_mp = (const float*)d_in[0];
    const float* z_sc = (const float*)d_in[1];
    const float* pos  = (const float*)d_in[2];
    float* out = (float*)d_out;

    ushort_t* zn = (ushort_t*)d_ws;                                       // 2 MB
    float* accum = (float*)((char*)d_ws + (size_t)2 * N * D * sizeof(ushort_t));   // 256 KB
    u64* mask = (u64*)((char*)accum + (size_t)4 * 2 * N * sizeof(float)); // 8 MB

    normalize_kernel<<<(2 * N) / 4, 256, 0, stream>>>(z_mp, z_sc, zn, accum);
    compress_kernel<<<2048, 256, 0, stream>>>(pos, mask);
    dim3 grid(N / 64, JSPLIT);
    contrast_main<<<grid, 256, 0, stream>>>(zn, (const unsigned*)mask, accum);
    finalize_kernel<<<1, 256, 0, stream>>>(accum, out);
}

// Round 10
// 174.684 us; speedup vs baseline: 1.6755x; 1.0483x over previous
//
#include <hip/hip_runtime.h>

#define N 8192
#define D 64
#define JSPLIT 16
#define JSTEPS (N / 64 / JSPLIT)   // 8 J-tiles of 64 cols per block

typedef unsigned short ushort_t;
typedef unsigned long long u64;
typedef __attribute__((ext_vector_type(8))) short bf16x8;
typedef __attribute__((ext_vector_type(4))) float f32x4;

// exp(cos/T) = exp(2*cos) = exp2(cos * 2/ln2). sqrt(2/ln2) is folded into BOTH
// normalized operands, so the MFMA dot product directly yields exp2's argument.
#define SQRT_2_OVER_LN2 1.6986436f

#if __has_builtin(__builtin_amdgcn_exp2f)
#define EXP2F(x) __builtin_amdgcn_exp2f(x)
#else
#define EXP2F(x) exp2f(x)
#endif

typedef __attribute__((address_space(1))) const unsigned int g_u32;
typedef __attribute__((address_space(3))) unsigned int       l_u32;

__device__ inline ushort_t f32_to_bf16(float f) {
    union { float f; unsigned u; } c; c.f = f;
    unsigned r = (c.u + 0x7FFFu + ((c.u >> 16) & 1u)) >> 16;
    return (ushort_t)r;
}

// ---------------- kernel 1: L2-normalize rows, scale, emit bf16 ---------
// Also zeroes the 64K-float accum buffer (blocks 0..255).
__global__ void normalize_kernel(const float* __restrict__ z_mp,
                                 const float* __restrict__ z_sc,
                                 ushort_t* __restrict__ zn,
                                 float* __restrict__ accum) {
    if (blockIdx.x < 256) accum[blockIdx.x * 256 + threadIdx.x] = 0.0f;
    int lane = threadIdx.x & 63;
    int row  = blockIdx.x * 4 + (threadIdx.x >> 6);
    const float* src = (row < N) ? z_mp : z_sc;
    int srow = row & (N - 1);
    float x = src[srow * D + lane];
    float s = x * x;
    #pragma unroll
    for (int m = 32; m; m >>= 1) s += __shfl_xor(s, m, 64);
    float n = sqrtf(s);
    float scale = SQRT_2_OVER_LN2 / fmaxf(n, 1e-12f);
    zn[row * D + lane] = f32_to_bf16(x * scale);
}

// ---------------- kernel 1b: compress pos (f32 0/1) -> bitmask ----------
// mask[row*128 + jw] bit j = (pos[row][jw*64+j] != 0). 8 MB total.
__global__ __launch_bounds__(256) void compress_kernel(
        const float* __restrict__ pos,
        u64* __restrict__ mask) {
    int lane = threadIdx.x & 63;
    size_t wv = (size_t)blockIdx.x * 4 + (threadIdx.x >> 6);
    size_t nw = (size_t)gridDim.x * 4;
    const size_t units = (size_t)N * N / 256;   // 256 cols per wave-iter
    for (size_t u = wv; u < units; u += nw) {
        const float* base = pos + u * 256 + lane;
        u64 w0 = __ballot(base[0]   > 0.5f);
        u64 w1 = __ballot(base[64]  > 0.5f);
        u64 w2 = __ballot(base[128] > 0.5f);
        u64 w3 = __ballot(base[192] > 0.5f);
        if (lane == 0) {
            u64* mb = mask + u * 4;
            mb[0] = w0; mb[1] = w1; mb[2] = w2; mb[3] = w3;
        }
    }
}

// ---------------- kernel 2: tiled 4-pair similarity + row accumulation --
// 4 waves/block on the same 64x64 (I,J) tile; wave w -> term (a=w>>1, b=w&1).
// B-panels staged to LDS per jj (double-buffered, pre-swizzled source so
// swizzled ds_read_b128 fragment reads are conflict-free) -- R9-verified.
// NEW: the block's ENTIRE mask need (64 rows x 16 u32 = 4 KB, loop-invariant)
// is staged to LDS once, so the inner loop has ZERO scattered global loads.
__global__ __launch_bounds__(256, 3) void contrast_main(
        const ushort_t* __restrict__ zn,
        const unsigned* __restrict__ mask32,
        float* __restrict__ accum) {
    __shared__ char lds[2][2][8192];      // [buf][panel(b-source)][64 x 128B]
    __shared__ unsigned mtile[64 * 16];   // mask rows I0..I0+64, 16 u32 each

    int lane = threadIdx.x & 63;
    int w    = threadIdx.x >> 6;       // wave 0..3
    int a = w >> 1, b = w & 1;         // 0=mp, 1=sc
    int term = (a == 0) ? (b == 0 ? 2 : 0) : (b == 0 ? 1 : 3);
    int rq = lane >> 4;                // 0..3
    int lc = lane & 15;                // 0..15
    unsigned sh = (unsigned)(lc & 7) * 4;   // nibble shift within u32

    const ushort_t* Az = zn + a * (N * D);
    int I0 = blockIdx.x * 64;
    int J0 = blockIdx.y * (N / JSPLIT);

    // one-time mask stage: wave w covers rows I0+16w..+16 (1 KB, linear).
    // lane l writes mtile bytes [w*1024 + l*16): row w*16+(l>>2), chunk l&3. ✓
    {
        const unsigned* gsrc = mask32 + (size_t)(I0 + w * 16 + (lane >> 2)) * (N / 32)
                                      + (J0 >> 5) + (lane & 3) * 4;
        __builtin_amdgcn_global_load_lds((g_u32*)gsrc,
                                         (l_u32*)((char*)mtile + w * 1024), 16, 0, 0);
    }

    // A fragments: row = I0 + 16r + lc, k = s*32 + rq*8 .. +8 (held all loop)
    bf16x8 af[4][2];
    #pragma unroll
    for (int r = 0; r < 4; ++r)
        #pragma unroll
        for (int s = 0; s < 2; ++s)
            af[r][s] = *(const bf16x8*)(Az + (I0 + 16 * r + lc) * D + s * 32 + rq * 8);

    // staging role: waves 0,1 -> panel 0 (mp); waves 2,3 -> panel 1 (sc).
    int pan  = w >> 1;
    int half = w & 1;
    const char* gpan = (const char*)(zn + (size_t)pan * N * D) + (size_t)J0 * 2 * D;

    #define STAGE(bufv, jjv) do {                                              \
        const char* gb_ = gpan + (size_t)(jjv) * 64 * 128;                     \
        char* lb_ = &lds[bufv][pan][half * 4096];                              \
        _Pragma("unroll")                                                      \
        for (int i_ = 0; i_ < 4; ++i_) {                                       \
            int row_ = half * 32 + i_ * 8 + (lane >> 3);                       \
            int bsw_ = ((lane & 7) * 16) ^ (((row_ >> 2) & 7) << 4);           \
            __builtin_amdgcn_global_load_lds(                                  \
                (g_u32*)(gb_ + row_ * 128 + bsw_),                             \
                (l_u32*)(lb_ + i_ * 1024), 16, 0, 0);                          \
        }                                                                      \
    } while (0)

    float rs_acc[4][4], ps_acc[4][4];
    #pragma unroll
    for (int r = 0; r < 4; ++r)
        #pragma unroll
        for (int e = 0; e < 4; ++e) { rs_acc[r][e] = 0.0f; ps_acc[r][e] = 0.0f; }

    // fragment ds_read byte offsets within the b-panel (swizzled):
    // frag (c,s): row = 4*lc+c, logical byte = s*64 + rq*16, swz = (lc&7)<<4
    const char* mypan_base[2] = { &lds[0][b][0], &lds[1][b][0] };
    unsigned fswz = ((unsigned)(lc & 7)) << 4;

    // per-lane base into the mask tile: row (rq*4), word (lc>>3)
    const unsigned* mt = &mtile[(rq * 4) * 16 + (lc >> 3)];

    STAGE(0, 0);
    __syncthreads();   // mask tile + buf0 ready

    #pragma unroll 1
    for (int jj = 0; jj < JSTEPS; ++jj) {
        int buf = jj & 1;
        if (jj + 1 < JSTEPS) STAGE(buf ^ 1, jj + 1);   // lands by next barrier

        // B fragments from LDS (swizzled, conflict-free)
        const char* pb = mypan_base[buf];
        bf16x8 bf[4][2];
        #pragma unroll
        for (int c = 0; c < 4; ++c)
            #pragma unroll
            for (int s = 0; s < 2; ++s)
                bf[c][s] = *(const bf16x8*)(pb + (4 * lc + c) * 128
                                              + (((unsigned)(s * 64 + rq * 16)) ^ fswz));

        #pragma unroll
        for (int r = 0; r < 4; ++r) {
            unsigned mwv[4];
            #pragma unroll
            for (int e = 0; e < 4; ++e)
                mwv[e] = mt[(16 * r + e) * 16 + jj * 2];   // ds_read_b32

            f32x4 acc[4];
            #pragma unroll
            for (int c = 0; c < 4; ++c) acc[c] = (f32x4){0.f, 0.f, 0.f, 0.f};
            #pragma unroll
            for (int s = 0; s < 2; ++s)
                #pragma unroll
                for (int c = 0; c < 4; ++c)
                    acc[c] = __builtin_amdgcn_mfma_f32_16x16x32_bf16(
                        af[r][s], bf[c][s], acc[c], 0, 0, 0);

            #pragma unroll
            for (int e = 0; e < 4; ++e) {
                unsigned nib = (mwv[e] >> sh) & 0xFu;
                float rs = rs_acc[r][e], ps = ps_acc[r][e];
                #pragma unroll
                for (int c = 0; c < 4; ++c) {
                    float eV = EXP2F(acc[c][e]);           // arg pre-scaled
                    rs += eV;
                    ps = fmaf((float)((nib >> c) & 1u), eV, ps);
                }
                rs_acc[r][e] = rs; ps_acc[r][e] = ps;
            }
        }
        __syncthreads();   // staging done + everyone finished reading buf
    }
    #undef STAGE

    // butterfly-reduce across the 16 lanes sharing each row (lane bits 0..3)
    #pragma unroll
    for (int r = 0; r < 4; ++r)
        #pragma unroll
        for (int e = 0; e < 4; ++e) {
            float rs = rs_acc[r][e], ps = ps_acc[r][e];
            #pragma unroll
            for (int m = 1; m < 16; m <<= 1) {
                rs += __shfl_xor(rs, m, 64);
                ps += __shfl_xor(ps, m, 64);
            }
            if (lc == 0) {
                int gi = I0 + 16 * r + rq * 4 + e;
                atomicAdd(&accum[term * 2 * N + gi],     rs);
                atomicAdd(&accum[term * 2 * N + N + gi], ps);
            }
        }
}

// ---------------- kernel 3: final loss reduction ------------------------
__global__ void finalize_kernel(const float* __restrict__ accum,
                                float* __restrict__ out) {
    __shared__ float red[256];
    float local = 0.0f;
    for (int i = threadIdx.x; i < N; i += 256) {
        float s = 0.0f;
        #pragma unroll
        for (int t = 0; t < 4; ++t) {
            float rs = accum[t * 2 * N + i];
            float ps = accum[t * 2 * N + N + i];
            s += logf(ps / (rs + 1e-8f));
        }
        local += s;
    }
    red[threadIdx.x] = local;
    __syncthreads();
    for (int m = 128; m; m >>= 1) {
        if (threadIdx.x < m) red[threadIdx.x] += red[threadIdx.x + m];
        __syncthreads();
    }
    if (threadIdx.x == 0) out[0] = -red[0] / (float)N;
}

extern "C" void kernel_launch(void* const* d_in, const int* in_sizes, int n_in,
                              void* d_out, int out_size, void* d_ws, size_t ws_size,
                              hipStream_t stream) {
    const float* z_mp = (const float*)d_in[0];
    const float* z_sc = (const float*)d_in[1];
    const float* pos  = (const float*)d_in[2];
    float* out = (float*)d_out;

    ushort_t* zn = (ushort_t*)d_ws;                                       // 2 MB
    float* accum = (float*)((char*)d_ws + (size_t)2 * N * D * sizeof(ushort_t));   // 256 KB
    u64* mask = (u64*)((char*)accum + (size_t)4 * 2 * N * sizeof(float)); // 8 MB

    normalize_kernel<<<(2 * N) / 4, 256, 0, stream>>>(z_mp, z_sc, zn, accum);
    compress_kernel<<<2048, 256, 0, stream>>>(pos, mask);
    dim3 grid(N / 64, JSPLIT);
    contrast_main<<<grid, 256, 0, stream>>>(zn, (const unsigned*)mask, accum);
    finalize_kernel<<<1, 256, 0, stream>>>(accum, out);
}